// Round 3
// baseline (307.420 us; speedup 1.0000x reference)
//
#include <hip/hip_runtime.h>
#include <hip/hip_bf16.h>
#include <stdint.h>

#define NPTS   131072
#define NANCH  1024
#define GRID   25
#define NCELL  (GRID*GRID)
#define CINV   0.25f
#define MAXP   512
#define MINP   4
#define IDXCAP 1024   // >= max possible inside-count (max E ~472, sigma ~22)

__device__ __forceinline__ int cell_of(float px, float py) {
    int cx = (int)(px * CINV); cx = cx < 0 ? 0 : (cx > GRID-1 ? GRID-1 : cx);
    int cy = (int)(py * CINV); cy = cy < 0 ? 0 : (cy > GRID-1 ? GRID-1 : cy);
    return cy * GRID + cx;
}

// ---------------- binning kernels ----------------

__global__ void k_hist(const float* __restrict__ pts, int* __restrict__ hist) {
    int i = blockIdx.x * blockDim.x + threadIdx.x;
    if (i >= NPTS) return;
    atomicAdd(&hist[cell_of(pts[3*i], pts[3*i+1])], 1);
}

__global__ void k_scan(const int* __restrict__ hist, int* __restrict__ cstart) {
    __shared__ int sc[1024];
    int t = threadIdx.x;
    int v = (t < NCELL) ? hist[t] : 0;
    sc[t] = v;
    __syncthreads();
    for (int off = 1; off < 1024; off <<= 1) {
        int x = (t >= off) ? sc[t - off] : 0;
        __syncthreads();
        sc[t] += x;
        __syncthreads();
    }
    if (t < NCELL) cstart[t] = sc[t] - v;       // exclusive
    if (t == NCELL-1) cstart[NCELL] = sc[t];    // total
}

__global__ void k_scatter(const float* __restrict__ pts,
                          const int* __restrict__ cstart, int* __restrict__ fill,
                          float* __restrict__ bx, float* __restrict__ by,
                          float* __restrict__ bz, int* __restrict__ bidx) {
    int i = blockIdx.x * blockDim.x + threadIdx.x;
    if (i >= NPTS) return;
    float px = pts[3*i], py = pts[3*i+1];
    int c = cell_of(px, py);
    int pos = cstart[c] + atomicAdd(&fill[c], 1);
    bx[pos] = px; by[pos] = py; bz[pos] = pts[3*i+2]; bidx[pos] = i;
}

// ---------------- main kernel: one block per anchor ----------------

__launch_bounds__(256, 4)   // <=128 VGPR: keep w2col[64] register-resident, 4 blocks/CU
__global__ void k_main(const float* __restrict__ pts,    // original order (fallback reload)
                       const float* __restrict__ anch,
                       const float* __restrict__ W1, const float* __restrict__ b1,
                       const float* __restrict__ W2, const float* __restrict__ b2,
                       const float* __restrict__ Wc, const float* __restrict__ bc,
                       const float* __restrict__ Wr, const float* __restrict__ br,
                       const float* __restrict__ bx, const float* __restrict__ by,
                       const float* __restrict__ bz, const int* __restrict__ bidx,
                       const int* __restrict__ cstart,
                       float* __restrict__ out) {
    __shared__ float spx[MAXP], spy[MAXP], spz[MAXP];  // gathered rel coords
    __shared__ float h1t[32][64];                      // h1 batch, [point][dim]
    __shared__ float w1s[3][64];
    __shared__ float b1s[64];
    __shared__ float gmax2[128];
    __shared__ int   sidx[IDXCAP];                     // original indices of inside pts
    __shared__ int   s_cnt;

    const int a   = blockIdx.x;
    const int tid = threadIdx.x;
    const float ax = anch[6*a],   ay = anch[6*a+1];
    const float w  = anch[6*a+3], l  = anch[6*a+4], hh = anch[6*a+5];
    const float hw = w * 0.5f, hl = l * 0.5f;
    const float x0 = ax - hw, x1 = ax + hw, y0 = ay - hl, y1 = ay + hl;

    if (tid == 0) s_cnt = 0;
    if (tid < 64) {
        w1s[0][tid] = W1[tid]; w1s[1][tid] = W1[64+tid]; w1s[2][tid] = W1[128+tid];
        b1s[tid] = b1[tid];
    }
    // W2 column for this thread's output dim, register-resident
    const int d = tid & 127;
    float w2col[64];
    #pragma unroll
    for (int i = 0; i < 64; i++) w2col[i] = W2[i*128 + d];
    const float b2reg = b2[d];
    __syncthreads();

    // ---- phase A: gather inside points from overlapping cells (unordered) ----
    int cx0 = (int)floorf(x0 * CINV); if (cx0 < 0) cx0 = 0;
    int cx1 = (int)floorf(x1 * CINV); if (cx1 > GRID-1) cx1 = GRID-1;
    int cy0 = (int)floorf(y0 * CINV); if (cy0 < 0) cy0 = 0;
    int cy1 = (int)floorf(y1 * CINV); if (cy1 > GRID-1) cy1 = GRID-1;

    for (int cy = cy0; cy <= cy1; cy++)
        for (int cx = cx0; cx <= cx1; cx++) {
            int c = cy * GRID + cx;
            int p0 = cstart[c], p1 = cstart[c+1];
            for (int base = p0; base < p1; base += 256) {
                int i = base + tid;
                if (i < p1) {
                    float px = bx[i], py = by[i], pz = bz[i];
                    bool ins = (px >= x0) & (px <= x1) & (py >= y0) & (py <= y1)
                             & (pz >= 0.f) & (pz <= hh);
                    if (ins) {
                        int pos = atomicAdd(&s_cnt, 1);
                        if (pos < MAXP)   { spx[pos] = px - ax; spy[pos] = py - ay; spz[pos] = pz; }
                        if (pos < IDXCAP) sidx[pos] = bidx[i];
                    }
                }
            }
        }
    __syncthreads();
    const int cnt = s_cnt;

    if (cnt < MINP) {               // zeroed row (valid==0), covers cnt==0
        if (tid < 5) out[5*a + tid] = 0.f;
        return;
    }

    // ---- rare fallback: cnt>512 needs "first 512 by original index" ----
    // Sort the <=IDXCAP gathered indices ascending (bitonic), keep smallest 512.
    if (cnt > MAXP) {
        for (int i = cnt + tid; i < IDXCAP; i += 256) sidx[i] = 0x7fffffff;
        __syncthreads();
        for (int k = 2; k <= IDXCAP; k <<= 1) {
            for (int j = k >> 1; j > 0; j >>= 1) {
                #pragma unroll
                for (int e = 0; e < IDXCAP/256; e++) {
                    int i = tid + e*256;
                    int partner = i ^ j;
                    if (partner > i) {
                        int va = sidx[i], vb = sidx[partner];
                        bool up = ((i & k) == 0);
                        if ((va > vb) == up) { sidx[i] = vb; sidx[partner] = va; }
                    }
                }
                __syncthreads();
            }
        }
        // reload coords of the 512 smallest-index points
        for (int i = tid; i < MAXP; i += 256) {
            int idx = sidx[i];
            spx[i] = pts[3*idx]   - ax;
            spy[i] = pts[3*idx+1] - ay;
            spz[i] = pts[3*idx+2];
        }
        __syncthreads();
    }

    // ---- pad to multiple of 32 with copies of point 0 (max-invariant) ----
    const int gathered = cnt < MAXP ? cnt : MAXP;
    const int padded   = (gathered + 31) & ~31;
    for (int i = gathered + tid; i < padded; i += 256) {
        spx[i] = spx[0]; spy[i] = spy[0]; spz[i] = spz[0];
    }
    __syncthreads();

    // ---- phase B: MLP + max over points, 32-point batches ----
    float gmax = 0.f;               // all h2 are relu'd >= 0
    const int sstream = tid >> 7;   // 2 point-streams of 16
    const int j  = tid & 63;        // h1 dim
    const int pw = tid >> 6;        // wave id: points pw*8 .. pw*8+7
    for (int pb = 0; pb < padded; pb += 32) {
        #pragma unroll
        for (int k = 0; k < 8; k++) {
            int p = pw * 8 + k;
            float qx = spx[pb+p], qy = spy[pb+p], qz = spz[pb+p];
            float v = fmaf(qz, w1s[2][j],
                      fmaf(qy, w1s[1][j],
                      fmaf(qx, w1s[0][j], b1s[j])));
            h1t[p][j] = fmaxf(v, 0.f);
        }
        __syncthreads();
        #pragma unroll
        for (int k = 0; k < 8; k++) {
            int p0 = sstream * 16 + 2*k;
            const float4* hp0 = (const float4*)&h1t[p0][0];     // broadcast reads
            const float4* hp1 = (const float4*)&h1t[p0+1][0];
            float acc0 = b2reg, acc1 = b2reg;
            #pragma unroll
            for (int i4 = 0; i4 < 16; i4++) {
                float4 h0 = hp0[i4], h1v = hp1[i4];
                acc0 = fmaf(h0.x,  w2col[4*i4+0], acc0);
                acc1 = fmaf(h1v.x, w2col[4*i4+0], acc1);
                acc0 = fmaf(h0.y,  w2col[4*i4+1], acc0);
                acc1 = fmaf(h1v.y, w2col[4*i4+1], acc1);
                acc0 = fmaf(h0.z,  w2col[4*i4+2], acc0);
                acc1 = fmaf(h1v.z, w2col[4*i4+2], acc1);
                acc0 = fmaf(h0.w,  w2col[4*i4+3], acc0);
                acc1 = fmaf(h1v.w, w2col[4*i4+3], acc1);
            }
            gmax = fmaxf(gmax, fmaxf(acc0, acc1));
        }
        __syncthreads();
    }

    // combine the two point-streams
    if (sstream == 1) gmax2[d] = gmax;
    __syncthreads();
    if (sstream == 0) gmax2[d] = fmaxf(gmax2[d], gmax);
    __syncthreads();

    // final heads: out = [g@Wc+bc, g@Wr+br]
    if (tid < 5) {
        const float* Wv; float bias; int stride;
        if (tid == 0) { Wv = Wc;            bias = bc[0];      stride = 1; }
        else          { Wv = Wr + (tid-1);  bias = br[tid-1];  stride = 4; }
        float acc = bias;
        for (int i = 0; i < 128; i++) acc = fmaf(gmax2[i], Wv[i*stride], acc);
        out[5*a + tid] = acc;
    }
}

// ---------------- launch ----------------

extern "C" void kernel_launch(void* const* d_in, const int* in_sizes, int n_in,
                              void* d_out, int out_size, void* d_ws, size_t ws_size,
                              hipStream_t stream) {
    const float* pts  = (const float*)d_in[0];
    const float* anch = (const float*)d_in[1];
    const float* W1   = (const float*)d_in[2];
    const float* b1   = (const float*)d_in[3];
    const float* W2   = (const float*)d_in[4];
    const float* b2   = (const float*)d_in[5];
    const float* Wc   = (const float*)d_in[6];
    const float* bc   = (const float*)d_in[7];
    const float* Wr   = (const float*)d_in[8];
    const float* br   = (const float*)d_in[9];
    float* out = (float*)d_out;

    char* ws = (char*)d_ws;
    int*   hist   = (int*)ws;                       // NCELL ints   (@0)
    int*   fill   = (int*)(ws + 4096);              // NCELL ints   (@4096)
    int*   cstart = (int*)(ws + 8192);              // NCELL+1 ints (@8192)
    float* bx     = (float*)(ws + 16384);           // NPTS floats
    float* by     = bx + NPTS;
    float* bz     = by + NPTS;
    int*   bidx   = (int*)(bz + NPTS);              // NPTS ints

    hipMemsetAsync(ws, 0, 8192, stream);            // hist + fill
    k_hist   <<<NPTS/256, 256, 0, stream>>>(pts, hist);
    k_scan   <<<1, 1024, 0, stream>>>(hist, cstart);
    k_scatter<<<NPTS/256, 256, 0, stream>>>(pts, cstart, fill, bx, by, bz, bidx);
    k_main   <<<NANCH, 256, 0, stream>>>(pts, anch, W1, b1, W2, b2, Wc, bc, Wr, br,
                                         bx, by, bz, bidx, cstart, out);
}

// Round 4
// 174.747 us; speedup vs baseline: 1.7592x; 1.7592x over previous
//
#include <hip/hip_runtime.h>
#include <hip/hip_bf16.h>
#include <stdint.h>

#define NPTS   131072
#define NANCH  1024
#define GRID   25
#define NCELL  (GRID*GRID)
#define CINV   0.25f
#define MAXP   512
#define MINP   4
#define IDXCAP 1024   // >= max possible inside-count (max E ~472, sigma ~22)

typedef __attribute__((ext_vector_type(8))) short bf16x8;
typedef __attribute__((ext_vector_type(4))) float f32x4;

__device__ __forceinline__ int cell_of(float px, float py) {
    int cx = (int)(px * CINV); cx = cx < 0 ? 0 : (cx > GRID-1 ? GRID-1 : cx);
    int cy = (int)(py * CINV); cy = cy < 0 ? 0 : (cy > GRID-1 ? GRID-1 : cy);
    return cy * GRID + cx;
}

__device__ __forceinline__ unsigned short f2bf(float f) {   // RNE
    union { float f; uint32_t u; } v; v.f = f;
    return (unsigned short)((v.u + 0x7fff + ((v.u >> 16) & 1)) >> 16);
}

// ---------------- binning kernels ----------------

__global__ void k_hist(const float* __restrict__ pts, int* __restrict__ hist) {
    int i = blockIdx.x * blockDim.x + threadIdx.x;
    if (i >= NPTS) return;
    atomicAdd(&hist[cell_of(pts[3*i], pts[3*i+1])], 1);
}

__global__ void k_scan(const int* __restrict__ hist, int* __restrict__ cstart) {
    __shared__ int sc[1024];
    int t = threadIdx.x;
    int v = (t < NCELL) ? hist[t] : 0;
    sc[t] = v;
    __syncthreads();
    for (int off = 1; off < 1024; off <<= 1) {
        int x = (t >= off) ? sc[t - off] : 0;
        __syncthreads();
        sc[t] += x;
        __syncthreads();
    }
    if (t < NCELL) cstart[t] = sc[t] - v;       // exclusive
    if (t == NCELL-1) cstart[NCELL] = sc[t];    // total
}

__global__ void k_scatter(const float* __restrict__ pts,
                          const int* __restrict__ cstart, int* __restrict__ fill,
                          float* __restrict__ bx, float* __restrict__ by,
                          float* __restrict__ bz, int* __restrict__ bidx) {
    int i = blockIdx.x * blockDim.x + threadIdx.x;
    if (i >= NPTS) return;
    float px = pts[3*i], py = pts[3*i+1];
    int c = cell_of(px, py);
    int pos = cstart[c] + atomicAdd(&fill[c], 1);
    bx[pos] = px; by[pos] = py; bz[pos] = pts[3*i+2]; bidx[pos] = i;
}

// ---------------- main kernel: one block (4 waves) per anchor ----------------

__launch_bounds__(256, 4)
__global__ void k_main(const float* __restrict__ pts,    // original order (fallback reload)
                       const float* __restrict__ anch,
                       const float* __restrict__ W1, const float* __restrict__ b1,
                       const float* __restrict__ W2, const float* __restrict__ b2,
                       const float* __restrict__ Wc, const float* __restrict__ bc,
                       const float* __restrict__ Wr, const float* __restrict__ br,
                       const float* __restrict__ bx, const float* __restrict__ by,
                       const float* __restrict__ bz, const int* __restrict__ bidx,
                       const int* __restrict__ cstart,
                       float* __restrict__ out) {
    __shared__ float spx[MAXP], spy[MAXP], spz[MAXP];   // gathered rel coords (6KB)
    __shared__ int   sidx[IDXCAP];                      // orig indices (4KB)
    __shared__ unsigned short h1b[32*64];               // h1 chunk bf16, swizzled (4KB)
    __shared__ unsigned short w2t[128*64];              // W2^T bf16 [col][k], swizzled (16KB)
    __shared__ float w1s[3][64];
    __shared__ float b1s[64];
    __shared__ float gmax2[128];
    __shared__ int   s_cnt;

    const int a    = blockIdx.x;
    const int tid  = threadIdx.x;
    const int lane = tid & 63;
    const int wv   = tid >> 6;

    const float ax = anch[6*a],   ay = anch[6*a+1];
    const float w  = anch[6*a+3], l  = anch[6*a+4], hh = anch[6*a+5];
    const float hw = w * 0.5f, hl = l * 0.5f;
    const float x0 = ax - hw, x1 = ax + hw, y0 = ay - hl, y1 = ay + hl;

    if (tid == 0) s_cnt = 0;
    if (tid < 64) {
        w1s[0][tid] = W1[tid]; w1s[1][tid] = W1[64+tid]; w1s[2][tid] = W1[128+tid];
        b1s[tid] = b1[tid];
    }
    // stage W2^T into LDS as bf16 [col][64 k], XOR-swizzled (^(col&7)<<3 in ushort units)
    {
        const int col = tid >> 1, k0 = (tid & 1) * 32;
        #pragma unroll
        for (int kk = 0; kk < 32; kk += 2) {
            int k = k0 + kk;
            float f0 = W2[k*128 + col], f1 = W2[(k+1)*128 + col];
            uint32_t pk = (uint32_t)f2bf(f0) | ((uint32_t)f2bf(f1) << 16);
            int idx = (col*64 + k) ^ ((col & 7) << 3);
            *(uint32_t*)&w2t[idx] = pk;
        }
    }
    __syncthreads();

    // ---- phase A: gather inside points from overlapping cells (unordered) ----
    int cx0 = (int)floorf(x0 * CINV); if (cx0 < 0) cx0 = 0;
    int cx1 = (int)floorf(x1 * CINV); if (cx1 > GRID-1) cx1 = GRID-1;
    int cy0 = (int)floorf(y0 * CINV); if (cy0 < 0) cy0 = 0;
    int cy1 = (int)floorf(y1 * CINV); if (cy1 > GRID-1) cy1 = GRID-1;

    for (int cy = cy0; cy <= cy1; cy++)
        for (int cx = cx0; cx <= cx1; cx++) {
            int c = cy * GRID + cx;
            int p0 = cstart[c], p1 = cstart[c+1];
            for (int base = p0; base < p1; base += 256) {
                int i = base + tid;
                if (i < p1) {
                    float px = bx[i], py = by[i], pz = bz[i];
                    bool ins = (px >= x0) & (px <= x1) & (py >= y0) & (py <= y1)
                             & (pz >= 0.f) & (pz <= hh);
                    if (ins) {
                        int pos = atomicAdd(&s_cnt, 1);
                        if (pos < MAXP)   { spx[pos] = px - ax; spy[pos] = py - ay; spz[pos] = pz; }
                        if (pos < IDXCAP) sidx[pos] = bidx[i];
                    }
                }
            }
        }
    __syncthreads();
    const int cnt = s_cnt;

    if (cnt < MINP) {               // zeroed row (valid==0), covers cnt==0
        if (tid < 5) out[5*a + tid] = 0.f;
        return;
    }

    // ---- rare fallback: cnt>512 needs "first 512 by original index" ----
    if (cnt > MAXP) {
        for (int i = cnt + tid; i < IDXCAP; i += 256) sidx[i] = 0x7fffffff;
        __syncthreads();
        for (int k = 2; k <= IDXCAP; k <<= 1) {
            for (int j = k >> 1; j > 0; j >>= 1) {
                #pragma unroll
                for (int e = 0; e < IDXCAP/256; e++) {
                    int i = tid + e*256;
                    int partner = i ^ j;
                    if (partner > i) {
                        int va = sidx[i], vb = sidx[partner];
                        bool up = ((i & k) == 0);
                        if ((va > vb) == up) { sidx[i] = vb; sidx[partner] = va; }
                    }
                }
                __syncthreads();
            }
        }
        for (int i = tid; i < MAXP; i += 256) {
            int idx = sidx[i];
            spx[i] = pts[3*idx]   - ax;
            spy[i] = pts[3*idx+1] - ay;
            spz[i] = pts[3*idx+2];
        }
        __syncthreads();
    }

    // ---- pad to multiple of 32 with copies of point 0 (max-invariant) ----
    const int gathered = cnt < MAXP ? cnt : MAXP;
    const int padded   = (gathered + 31) & ~31;
    for (int i = gathered + tid; i < padded; i += 256) {
        spx[i] = spx[0]; spy[i] = spy[0]; spz[i] = spz[0];
    }
    __syncthreads();

    // ---- B-fragments (W2^T), register-resident, reused across all chunks ----
    // wave wv owns output cols nt*16+(lane&15) for nt = wv and wv+4
    bf16x8 b00, b01, b10, b11;   // [ntid][kt]
    {
        const int l15 = lane & 15, kb = (lane >> 4) * 8;
        int c0 = wv*16 + l15, c1 = (wv+4)*16 + l15;
        int i00 = (c0*64 +  0 + kb) ^ ((c0 & 7) << 3);
        int i01 = (c0*64 + 32 + kb) ^ ((c0 & 7) << 3);
        int i10 = (c1*64 +  0 + kb) ^ ((c1 & 7) << 3);
        int i11 = (c1*64 + 32 + kb) ^ ((c1 & 7) << 3);
        b00 = *(const bf16x8*)&w2t[i00];
        b01 = *(const bf16x8*)&w2t[i01];
        b10 = *(const bf16x8*)&w2t[i10];
        b11 = *(const bf16x8*)&w2t[i11];
    }

    // ---- phase B: layer1 (fp32->bf16) + MFMA layer2, 32-point chunks ----
    float gm0 = -INFINITY, gm1 = -INFINITY;   // raw max (bias+relu deferred)
    const int pairid = tid & 31;              // h1 dims 2*pairid, 2*pairid+1
    const int rbase  = tid >> 5;              // 0..7
    const int l15 = lane & 15, kb = (lane >> 4) * 8;

    for (int pb = 0; pb < padded; pb += 32) {
        // layer 1: h1[32][64] bf16 into swizzled LDS
        #pragma unroll
        for (int pass = 0; pass < 4; pass++) {
            int row = pass*8 + rbase;
            int p = pb + row;
            float qx = spx[p], qy = spy[p], qz = spz[p];
            int d0 = pairid * 2;
            float v0 = fmaf(qz, w1s[2][d0],   fmaf(qy, w1s[1][d0],   fmaf(qx, w1s[0][d0],   b1s[d0])));
            float v1 = fmaf(qz, w1s[2][d0+1], fmaf(qy, w1s[1][d0+1], fmaf(qx, w1s[0][d0+1], b1s[d0+1])));
            v0 = fmaxf(v0, 0.f); v1 = fmaxf(v1, 0.f);
            uint32_t pk = (uint32_t)f2bf(v0) | ((uint32_t)f2bf(v1) << 16);
            int idx = (row*64 + d0) ^ ((row & 7) << 3);
            *(uint32_t*)&h1b[idx] = pk;
        }
        __syncthreads();

        // A-fragments: rows mt*16+(lane&15), k = kt*32 + (lane>>4)*8 .. +8
        int r0 = l15, r1 = 16 + l15;
        int a00i = (r0*64 +  0 + kb) ^ ((r0 & 7) << 3);
        int a01i = (r0*64 + 32 + kb) ^ ((r0 & 7) << 3);
        int a10i = (r1*64 +  0 + kb) ^ ((r1 & 7) << 3);
        int a11i = (r1*64 + 32 + kb) ^ ((r1 & 7) << 3);
        bf16x8 a00 = *(const bf16x8*)&h1b[a00i];
        bf16x8 a01 = *(const bf16x8*)&h1b[a01i];
        bf16x8 a10 = *(const bf16x8*)&h1b[a10i];
        bf16x8 a11 = *(const bf16x8*)&h1b[a11i];

        f32x4 z = {0.f, 0.f, 0.f, 0.f};
        f32x4 c;
        c = __builtin_amdgcn_mfma_f32_16x16x32_bf16(a00, b00, z, 0, 0, 0);
        c = __builtin_amdgcn_mfma_f32_16x16x32_bf16(a01, b01, c, 0, 0, 0);
        gm0 = fmaxf(gm0, fmaxf(fmaxf(c[0], c[1]), fmaxf(c[2], c[3])));
        c = __builtin_amdgcn_mfma_f32_16x16x32_bf16(a10, b00, z, 0, 0, 0);
        c = __builtin_amdgcn_mfma_f32_16x16x32_bf16(a11, b01, c, 0, 0, 0);
        gm0 = fmaxf(gm0, fmaxf(fmaxf(c[0], c[1]), fmaxf(c[2], c[3])));
        c = __builtin_amdgcn_mfma_f32_16x16x32_bf16(a00, b10, z, 0, 0, 0);
        c = __builtin_amdgcn_mfma_f32_16x16x32_bf16(a01, b11, c, 0, 0, 0);
        gm1 = fmaxf(gm1, fmaxf(fmaxf(c[0], c[1]), fmaxf(c[2], c[3])));
        c = __builtin_amdgcn_mfma_f32_16x16x32_bf16(a10, b10, z, 0, 0, 0);
        c = __builtin_amdgcn_mfma_f32_16x16x32_bf16(a11, b11, c, 0, 0, 0);
        gm1 = fmaxf(gm1, fmaxf(fmaxf(c[0], c[1]), fmaxf(c[2], c[3])));
        __syncthreads();   // before next chunk overwrites h1b
    }

    // reduce across the 4 row-groups (lanes L, L^16, L^32, L^48 share col)
    gm0 = fmaxf(gm0, __shfl_xor(gm0, 16)); gm0 = fmaxf(gm0, __shfl_xor(gm0, 32));
    gm1 = fmaxf(gm1, __shfl_xor(gm1, 16)); gm1 = fmaxf(gm1, __shfl_xor(gm1, 32));
    if (lane < 16) {
        gmax2[wv*16     + lane] = gm0;
        gmax2[(wv+4)*16 + lane] = gm1;
    }
    __syncthreads();
    if (tid < 128) gmax2[tid] = fmaxf(gmax2[tid] + b2[tid], 0.f);   // bias + relu
    __syncthreads();

    // final heads: out = [g@Wc+bc, g@Wr+br]
    if (tid < 5) {
        const float* Wv; float bias; int stride;
        if (tid == 0) { Wv = Wc;            bias = bc[0];      stride = 1; }
        else          { Wv = Wr + (tid-1);  bias = br[tid-1];  stride = 4; }
        float acc = bias;
        for (int i = 0; i < 128; i++) acc = fmaf(gmax2[i], Wv[i*stride], acc);
        out[5*a + tid] = acc;
    }
}

// ---------------- launch ----------------

extern "C" void kernel_launch(void* const* d_in, const int* in_sizes, int n_in,
                              void* d_out, int out_size, void* d_ws, size_t ws_size,
                              hipStream_t stream) {
    const float* pts  = (const float*)d_in[0];
    const float* anch = (const float*)d_in[1];
    const float* W1   = (const float*)d_in[2];
    const float* b1   = (const float*)d_in[3];
    const float* W2   = (const float*)d_in[4];
    const float* b2   = (const float*)d_in[5];
    const float* Wc   = (const float*)d_in[6];
    const float* bc   = (const float*)d_in[7];
    const float* Wr   = (const float*)d_in[8];
    const float* br   = (const float*)d_in[9];
    float* out = (float*)d_out;

    char* ws = (char*)d_ws;
    int*   hist   = (int*)ws;                       // NCELL ints   (@0)
    int*   fill   = (int*)(ws + 4096);              // NCELL ints   (@4096)
    int*   cstart = (int*)(ws + 8192);              // NCELL+1 ints (@8192)
    float* bx     = (float*)(ws + 16384);           // NPTS floats
    float* by     = bx + NPTS;
    float* bz     = by + NPTS;
    int*   bidx   = (int*)(bz + NPTS);              // NPTS ints

    hipMemsetAsync(ws, 0, 8192, stream);            // hist + fill
    k_hist   <<<NPTS/256, 256, 0, stream>>>(pts, hist);
    k_scan   <<<1, 1024, 0, stream>>>(hist, cstart);
    k_scatter<<<NPTS/256, 256, 0, stream>>>(pts, cstart, fill, bx, by, bz, bidx);
    k_main   <<<NANCH, 256, 0, stream>>>(pts, anch, W1, b1, W2, b2, Wc, bc, Wr, br,
                                         bx, by, bz, bidx, cstart, out);
}

// Round 5
// 109.547 us; speedup vs baseline: 2.8063x; 1.5952x over previous
//
#include <hip/hip_runtime.h>
#include <hip/hip_bf16.h>
#include <stdint.h>

#define NPTS   131072
#define NANCH  1024
#define GRID   25
#define NCELL  (GRID*GRID)
#define CINV   0.25f
#define MAXP   512
#define MINP   4
#define IDXCAP 1024   // >= max possible inside-count (max E ~472, sigma ~22)
#define HB     128    // histogram blocks
#define PPB    (NPTS/HB)   // 1024 points per block

typedef __attribute__((ext_vector_type(8))) short bf16x8;
typedef __attribute__((ext_vector_type(4))) float f32x4;

__device__ __forceinline__ int cell_of(float px, float py) {
    int cx = (int)(px * CINV); cx = cx < 0 ? 0 : (cx > GRID-1 ? GRID-1 : cx);
    int cy = (int)(py * CINV); cy = cy < 0 ? 0 : (cy > GRID-1 ? GRID-1 : cy);
    return cy * GRID + cx;
}

__device__ __forceinline__ unsigned short f2bf(float f) {   // RNE
    union { float f; uint32_t u; } v; v.f = f;
    return (unsigned short)((v.u + 0x7fff + ((v.u >> 16) & 1)) >> 16);
}

// ---------------- binning: per-block counting sort (no global atomics) ----------------

__global__ __launch_bounds__(256) void k_hist(const float* __restrict__ pts,
                                              int* __restrict__ blockhist) {
    __shared__ int lh[NCELL];
    const int b = blockIdx.x, tid = threadIdx.x;
    for (int i = tid; i < NCELL; i += 256) lh[i] = 0;
    __syncthreads();
    const int base = b * PPB;
    #pragma unroll
    for (int k = 0; k < PPB/256; k++) {
        int i = base + k*256 + tid;
        atomicAdd(&lh[cell_of(pts[3*i], pts[3*i+1])], 1);
    }
    __syncthreads();
    for (int i = tid; i < NCELL; i += 256) blockhist[b*NCELL + i] = lh[i];
}

__global__ __launch_bounds__(1024) void k_scan(const int* __restrict__ blockhist,
                                               int* __restrict__ blockpre,
                                               int* __restrict__ cstart) {
    __shared__ int sc[1024];
    const int c = threadIdx.x;
    int acc = 0;
    if (c < NCELL) {
        #pragma unroll 8
        for (int b = 0; b < HB; b++) {          // per-cell prefix over blocks
            int v = blockhist[b*NCELL + c];
            blockpre[b*NCELL + c] = acc;
            acc += v;
        }
    }
    sc[c] = (c < NCELL) ? acc : 0;
    __syncthreads();
    for (int off = 1; off < 1024; off <<= 1) {  // inclusive scan over cells
        int x = (c >= off) ? sc[c - off] : 0;
        __syncthreads();
        sc[c] += x;
        __syncthreads();
    }
    if (c < NCELL) cstart[c] = sc[c] - acc;     // exclusive
    if (c == NCELL-1) cstart[NCELL] = sc[c];    // total
}

__global__ __launch_bounds__(256) void k_scatter(const float* __restrict__ pts,
                                                 const int* __restrict__ blockpre,
                                                 const int* __restrict__ cstart,
                                                 float4* __restrict__ binned) {
    __shared__ int lh[NCELL];
    __shared__ int lbase[NCELL];
    const int b = blockIdx.x, tid = threadIdx.x;
    for (int i = tid; i < NCELL; i += 256) {
        lh[i] = 0;
        lbase[i] = cstart[i] + blockpre[b*NCELL + i];
    }
    __syncthreads();
    const int base = b * PPB;
    #pragma unroll
    for (int k = 0; k < PPB/256; k++) {
        int i = base + k*256 + tid;
        float px = pts[3*i], py = pts[3*i+1], pz = pts[3*i+2];
        int c = cell_of(px, py);
        int r = atomicAdd(&lh[c], 1);           // LDS atomic, ~1.6/cell contention
        binned[lbase[c] + r] = make_float4(px, py, pz, __int_as_float(i));
    }
}

// ---------------- main kernel: one block (4 waves) per anchor ----------------

__launch_bounds__(256, 4)
__global__ void k_main(const float* __restrict__ pts,    // original order (fallback reload)
                       const float* __restrict__ anch,
                       const float* __restrict__ W1, const float* __restrict__ b1,
                       const float* __restrict__ W2, const float* __restrict__ b2,
                       const float* __restrict__ Wc, const float* __restrict__ bc,
                       const float* __restrict__ Wr, const float* __restrict__ br,
                       const float4* __restrict__ binned,
                       const int* __restrict__ cstart,
                       float* __restrict__ out) {
    __shared__ float spx[MAXP], spy[MAXP], spz[MAXP];   // gathered rel coords (6KB)
    __shared__ int   sidx[IDXCAP];                      // orig indices (4KB)
    __shared__ unsigned short h1b[32*64];               // h1 chunk bf16, swizzled (4KB)
    __shared__ unsigned short w2t[128*64];              // W2^T bf16 [col][k], swizzled (16KB)
    __shared__ float w1s[3][64];
    __shared__ float b1s[64];
    __shared__ float gmax2[128];
    __shared__ int   s_cnt;

    const int a    = blockIdx.x;
    const int tid  = threadIdx.x;
    const int lane = tid & 63;
    const int wv   = tid >> 6;

    const float ax = anch[6*a],   ay = anch[6*a+1];
    const float w  = anch[6*a+3], l  = anch[6*a+4], hh = anch[6*a+5];
    const float hw = w * 0.5f, hl = l * 0.5f;
    const float x0 = ax - hw, x1 = ax + hw, y0 = ay - hl, y1 = ay + hl;

    if (tid == 0) s_cnt = 0;
    if (tid < 64) {
        w1s[0][tid] = W1[tid]; w1s[1][tid] = W1[64+tid]; w1s[2][tid] = W1[128+tid];
        b1s[tid] = b1[tid];
    }
    // stage W2^T into LDS as bf16 [col][64 k], XOR-swizzled (^(col&7)<<3 in ushort units)
    {
        const int col = tid >> 1, k0 = (tid & 1) * 32;
        #pragma unroll
        for (int kk = 0; kk < 32; kk += 2) {
            int k = k0 + kk;
            float f0 = W2[k*128 + col], f1 = W2[(k+1)*128 + col];
            uint32_t pk = (uint32_t)f2bf(f0) | ((uint32_t)f2bf(f1) << 16);
            int idx = (col*64 + k) ^ ((col & 7) << 3);
            *(uint32_t*)&w2t[idx] = pk;
        }
    }
    __syncthreads();

    // ---- phase A: gather inside points from overlapping cells (unordered) ----
    int cx0 = (int)floorf(x0 * CINV); if (cx0 < 0) cx0 = 0;
    int cx1 = (int)floorf(x1 * CINV); if (cx1 > GRID-1) cx1 = GRID-1;
    int cy0 = (int)floorf(y0 * CINV); if (cy0 < 0) cy0 = 0;
    int cy1 = (int)floorf(y1 * CINV); if (cy1 > GRID-1) cy1 = GRID-1;

    for (int cy = cy0; cy <= cy1; cy++)
        for (int cx = cx0; cx <= cx1; cx++) {
            int c = cy * GRID + cx;
            int p0 = cstart[c], p1 = cstart[c+1];
            for (int base = p0; base < p1; base += 256) {
                int i = base + tid;
                if (i < p1) {
                    float4 P = binned[i];
                    float px = P.x, py = P.y, pz = P.z;
                    bool ins = (px >= x0) & (px <= x1) & (py >= y0) & (py <= y1)
                             & (pz >= 0.f) & (pz <= hh);
                    if (ins) {
                        int pos = atomicAdd(&s_cnt, 1);
                        if (pos < MAXP)   { spx[pos] = px - ax; spy[pos] = py - ay; spz[pos] = pz; }
                        if (pos < IDXCAP) sidx[pos] = __float_as_int(P.w);
                    }
                }
            }
        }
    __syncthreads();
    const int cnt = s_cnt;

    if (cnt < MINP) {               // zeroed row (valid==0), covers cnt==0
        if (tid < 5) out[5*a + tid] = 0.f;
        return;
    }

    // ---- rare fallback: cnt>512 needs "first 512 by original index" ----
    if (cnt > MAXP) {
        for (int i = cnt + tid; i < IDXCAP; i += 256) sidx[i] = 0x7fffffff;
        __syncthreads();
        for (int k = 2; k <= IDXCAP; k <<= 1) {
            for (int j = k >> 1; j > 0; j >>= 1) {
                #pragma unroll
                for (int e = 0; e < IDXCAP/256; e++) {
                    int i = tid + e*256;
                    int partner = i ^ j;
                    if (partner > i) {
                        int va = sidx[i], vb = sidx[partner];
                        bool up = ((i & k) == 0);
                        if ((va > vb) == up) { sidx[i] = vb; sidx[partner] = va; }
                    }
                }
                __syncthreads();
            }
        }
        for (int i = tid; i < MAXP; i += 256) {
            int idx = sidx[i];
            spx[i] = pts[3*idx]   - ax;
            spy[i] = pts[3*idx+1] - ay;
            spz[i] = pts[3*idx+2];
        }
        __syncthreads();
    }

    // ---- pad to multiple of 32 with copies of point 0 (max-invariant) ----
    const int gathered = cnt < MAXP ? cnt : MAXP;
    const int padded   = (gathered + 31) & ~31;
    for (int i = gathered + tid; i < padded; i += 256) {
        spx[i] = spx[0]; spy[i] = spy[0]; spz[i] = spz[0];
    }
    __syncthreads();

    // ---- B-fragments (W2^T), register-resident, reused across all chunks ----
    // wave wv owns output cols nt*16+(lane&15) for nt = wv and wv+4
    bf16x8 b00, b01, b10, b11;   // [ntid][kt]
    {
        const int l15 = lane & 15, kb = (lane >> 4) * 8;
        int c0 = wv*16 + l15, c1 = (wv+4)*16 + l15;
        int i00 = (c0*64 +  0 + kb) ^ ((c0 & 7) << 3);
        int i01 = (c0*64 + 32 + kb) ^ ((c0 & 7) << 3);
        int i10 = (c1*64 +  0 + kb) ^ ((c1 & 7) << 3);
        int i11 = (c1*64 + 32 + kb) ^ ((c1 & 7) << 3);
        b00 = *(const bf16x8*)&w2t[i00];
        b01 = *(const bf16x8*)&w2t[i01];
        b10 = *(const bf16x8*)&w2t[i10];
        b11 = *(const bf16x8*)&w2t[i11];
    }

    // ---- phase B: layer1 (fp32->bf16) + MFMA layer2, 32-point chunks ----
    float gm0 = -INFINITY, gm1 = -INFINITY;   // raw max (bias+relu deferred)
    const int pairid = tid & 31;              // h1 dims 2*pairid, 2*pairid+1
    const int rbase  = tid >> 5;              // 0..7
    const int l15 = lane & 15, kb = (lane >> 4) * 8;

    for (int pb = 0; pb < padded; pb += 32) {
        // layer 1: h1[32][64] bf16 into swizzled LDS
        #pragma unroll
        for (int pass = 0; pass < 4; pass++) {
            int row = pass*8 + rbase;
            int p = pb + row;
            float qx = spx[p], qy = spy[p], qz = spz[p];
            int d0 = pairid * 2;
            float v0 = fmaf(qz, w1s[2][d0],   fmaf(qy, w1s[1][d0],   fmaf(qx, w1s[0][d0],   b1s[d0])));
            float v1 = fmaf(qz, w1s[2][d0+1], fmaf(qy, w1s[1][d0+1], fmaf(qx, w1s[0][d0+1], b1s[d0+1])));
            v0 = fmaxf(v0, 0.f); v1 = fmaxf(v1, 0.f);
            uint32_t pk = (uint32_t)f2bf(v0) | ((uint32_t)f2bf(v1) << 16);
            int idx = (row*64 + d0) ^ ((row & 7) << 3);
            *(uint32_t*)&h1b[idx] = pk;
        }
        __syncthreads();

        // A-fragments: rows mt*16+(lane&15), k = kt*32 + (lane>>4)*8 .. +8
        int r0 = l15, r1 = 16 + l15;
        int a00i = (r0*64 +  0 + kb) ^ ((r0 & 7) << 3);
        int a01i = (r0*64 + 32 + kb) ^ ((r0 & 7) << 3);
        int a10i = (r1*64 +  0 + kb) ^ ((r1 & 7) << 3);
        int a11i = (r1*64 + 32 + kb) ^ ((r1 & 7) << 3);
        bf16x8 a00 = *(const bf16x8*)&h1b[a00i];
        bf16x8 a01 = *(const bf16x8*)&h1b[a01i];
        bf16x8 a10 = *(const bf16x8*)&h1b[a10i];
        bf16x8 a11 = *(const bf16x8*)&h1b[a11i];

        f32x4 z = {0.f, 0.f, 0.f, 0.f};
        f32x4 c;
        c = __builtin_amdgcn_mfma_f32_16x16x32_bf16(a00, b00, z, 0, 0, 0);
        c = __builtin_amdgcn_mfma_f32_16x16x32_bf16(a01, b01, c, 0, 0, 0);
        gm0 = fmaxf(gm0, fmaxf(fmaxf(c[0], c[1]), fmaxf(c[2], c[3])));
        c = __builtin_amdgcn_mfma_f32_16x16x32_bf16(a10, b00, z, 0, 0, 0);
        c = __builtin_amdgcn_mfma_f32_16x16x32_bf16(a11, b01, c, 0, 0, 0);
        gm0 = fmaxf(gm0, fmaxf(fmaxf(c[0], c[1]), fmaxf(c[2], c[3])));
        c = __builtin_amdgcn_mfma_f32_16x16x32_bf16(a00, b10, z, 0, 0, 0);
        c = __builtin_amdgcn_mfma_f32_16x16x32_bf16(a01, b11, c, 0, 0, 0);
        gm1 = fmaxf(gm1, fmaxf(fmaxf(c[0], c[1]), fmaxf(c[2], c[3])));
        c = __builtin_amdgcn_mfma_f32_16x16x32_bf16(a10, b10, z, 0, 0, 0);
        c = __builtin_amdgcn_mfma_f32_16x16x32_bf16(a11, b11, c, 0, 0, 0);
        gm1 = fmaxf(gm1, fmaxf(fmaxf(c[0], c[1]), fmaxf(c[2], c[3])));
        __syncthreads();   // before next chunk overwrites h1b
    }

    // reduce across the 4 row-groups (lanes L, L^16, L^32, L^48 share col)
    gm0 = fmaxf(gm0, __shfl_xor(gm0, 16)); gm0 = fmaxf(gm0, __shfl_xor(gm0, 32));
    gm1 = fmaxf(gm1, __shfl_xor(gm1, 16)); gm1 = fmaxf(gm1, __shfl_xor(gm1, 32));
    if (lane < 16) {
        gmax2[wv*16     + lane] = gm0;
        gmax2[(wv+4)*16 + lane] = gm1;
    }
    __syncthreads();
    if (tid < 128) gmax2[tid] = fmaxf(gmax2[tid] + b2[tid], 0.f);   // bias + relu
    __syncthreads();

    // final heads: out = [g@Wc+bc, g@Wr+br]
    if (tid < 5) {
        const float* Wv; float bias; int stride;
        if (tid == 0) { Wv = Wc;            bias = bc[0];      stride = 1; }
        else          { Wv = Wr + (tid-1);  bias = br[tid-1];  stride = 4; }
        float acc = bias;
        for (int i = 0; i < 128; i++) acc = fmaf(gmax2[i], Wv[i*stride], acc);
        out[5*a + tid] = acc;
    }
}

// ---------------- launch ----------------

extern "C" void kernel_launch(void* const* d_in, const int* in_sizes, int n_in,
                              void* d_out, int out_size, void* d_ws, size_t ws_size,
                              hipStream_t stream) {
    const float* pts  = (const float*)d_in[0];
    const float* anch = (const float*)d_in[1];
    const float* W1   = (const float*)d_in[2];
    const float* b1   = (const float*)d_in[3];
    const float* W2   = (const float*)d_in[4];
    const float* b2   = (const float*)d_in[5];
    const float* Wc   = (const float*)d_in[6];
    const float* bc   = (const float*)d_in[7];
    const float* Wr   = (const float*)d_in[8];
    const float* br   = (const float*)d_in[9];
    float* out = (float*)d_out;

    char* ws = (char*)d_ws;
    float4* binned    = (float4*)ws;                        // NPTS float4 (2MB, 16B-aligned @0)
    int*    blockhist = (int*)(ws + (size_t)NPTS*16);       // HB*NCELL ints (320KB)
    int*    blockpre  = blockhist + HB*NCELL;               // HB*NCELL ints (320KB)
    int*    cstart    = blockpre  + HB*NCELL;               // NCELL+1 ints

    k_hist   <<<HB, 256, 0, stream>>>(pts, blockhist);
    k_scan   <<<1, 1024, 0, stream>>>(blockhist, blockpre, cstart);
    k_scatter<<<HB, 256, 0, stream>>>(pts, blockpre, cstart, binned);
    k_main   <<<NANCH, 256, 0, stream>>>(pts, anch, W1, b1, W2, b2, Wc, bc, Wr, br,
                                         binned, cstart, out);
}

// Round 6
// 109.397 us; speedup vs baseline: 2.8101x; 1.0014x over previous
//
#include <hip/hip_runtime.h>
#include <hip/hip_bf16.h>
#include <stdint.h>

#define NPTS   131072
#define NANCH  1024
#define GRID   25
#define NCELL  (GRID*GRID)
#define CINV   0.25f
#define MAXP   512
#define MINP   4
#define IDXCAP 1024   // >= max possible inside-count (max E ~472, sigma ~22)
#define HB     128    // histogram blocks
#define PPB    (NPTS/HB)   // 1024 points per block

typedef __attribute__((ext_vector_type(8))) short bf16x8;
typedef __attribute__((ext_vector_type(4))) float f32x4;

__device__ __forceinline__ int cell_of(float px, float py) {
    int cx = (int)(px * CINV); cx = cx < 0 ? 0 : (cx > GRID-1 ? GRID-1 : cx);
    int cy = (int)(py * CINV); cy = cy < 0 ? 0 : (cy > GRID-1 ? GRID-1 : cy);
    return cy * GRID + cx;
}

__device__ __forceinline__ unsigned short f2bf(float f) {   // RNE
    union { float f; uint32_t u; } v; v.f = f;
    return (unsigned short)((v.u + 0x7fff + ((v.u >> 16) & 1)) >> 16);
}

// ---------------- binning: per-block counting sort (no global atomics) ----------------

// hist + per-point rank-within-(block,cell), saved so k_scatter needs no atomics
__global__ __launch_bounds__(256) void k_hist(const float* __restrict__ pts,
                                              int* __restrict__ blockhist,
                                              int* __restrict__ cellrank) {
    __shared__ int lh[NCELL];
    const int b = blockIdx.x, tid = threadIdx.x;
    for (int i = tid; i < NCELL; i += 256) lh[i] = 0;
    __syncthreads();
    const int base = b * PPB;
    #pragma unroll
    for (int k = 0; k < PPB/256; k++) {
        int i = base + k*256 + tid;
        int c = cell_of(pts[3*i], pts[3*i+1]);
        int r = atomicAdd(&lh[c], 1);           // LDS atomic, ~1.6/cell contention
        cellrank[i] = c | (r << 10);            // c<625 (10b), r<1024
    }
    __syncthreads();
    for (int i = tid; i < NCELL; i += 256) blockhist[b*NCELL + i] = lh[i];
}

// scan over blocks+cells; threads 640..895 (idle during the serial loop) also
// transpose W2 -> bf16 [128 col][64 k] into global for k_main's B-fragments
__global__ __launch_bounds__(1024) void k_scan(const int* __restrict__ blockhist,
                                               int* __restrict__ blockpre,
                                               int* __restrict__ cstart,
                                               const float* __restrict__ W2,
                                               unsigned short* __restrict__ w2tg) {
    __shared__ int sc[1024];
    const int c = threadIdx.x;
    int acc = 0;
    if (c < NCELL) {
        #pragma unroll 8
        for (int b = 0; b < HB; b++) {          // per-cell prefix over blocks
            int v = blockhist[b*NCELL + c];
            blockpre[b*NCELL + c] = acc;
            acc += v;
        }
    } else if (c >= 640 && c < 896) {           // W2^T bf16 prep (hidden)
        int u = c - 640;
        int col = u >> 1, ks = (u & 1) * 32;
        #pragma unroll
        for (int kk = 0; kk < 32; kk += 2) {
            int k = ks + kk;
            uint32_t pk = (uint32_t)f2bf(W2[k*128 + col])
                        | ((uint32_t)f2bf(W2[(k+1)*128 + col]) << 16);
            *(uint32_t*)&w2tg[col*64 + k] = pk;
        }
    }
    sc[c] = (c < NCELL) ? acc : 0;
    __syncthreads();
    for (int off = 1; off < 1024; off <<= 1) {  // inclusive scan over cells
        int x = (c >= off) ? sc[c - off] : 0;
        __syncthreads();
        sc[c] += x;
        __syncthreads();
    }
    if (c < NCELL) cstart[c] = sc[c] - acc;     // exclusive
    if (c == NCELL-1) cstart[NCELL] = sc[c];    // total
}

__global__ __launch_bounds__(256) void k_scatter(const float* __restrict__ pts,
                                                 const int* __restrict__ cellrank,
                                                 const int* __restrict__ blockpre,
                                                 const int* __restrict__ cstart,
                                                 float4* __restrict__ binned) {
    __shared__ int lbase[NCELL];
    const int b = blockIdx.x, tid = threadIdx.x;
    for (int i = tid; i < NCELL; i += 256)
        lbase[i] = cstart[i] + blockpre[b*NCELL + i];
    __syncthreads();
    const int base = b * PPB;
    #pragma unroll
    for (int k = 0; k < PPB/256; k++) {
        int i = base + k*256 + tid;
        int v = cellrank[i];
        int c = v & 1023, r = v >> 10;
        binned[lbase[c] + r] = make_float4(pts[3*i], pts[3*i+1], pts[3*i+2],
                                           __int_as_float(i));
    }
}

// ---------------- main kernel: one block (4 waves) per anchor ----------------

__launch_bounds__(256, 4)
__global__ void k_main(const float* __restrict__ pts,    // original order (fallback reload)
                       const float* __restrict__ anch,
                       const float* __restrict__ W1, const float* __restrict__ b1,
                       const float* __restrict__ b2,
                       const float* __restrict__ Wc, const float* __restrict__ bc,
                       const float* __restrict__ Wr, const float* __restrict__ br,
                       const unsigned short* __restrict__ w2tg,
                       const float4* __restrict__ binned,
                       const int* __restrict__ cstart,
                       float* __restrict__ out) {
    __shared__ float spx[MAXP], spy[MAXP], spz[MAXP];   // gathered rel coords (6KB)
    __shared__ int   sidx[IDXCAP];                      // orig indices (4KB)
    __shared__ unsigned short h1b[64*64];               // h1 chunk bf16, swizzled (8KB)
    __shared__ float w1s[3][64];
    __shared__ float b1s[64];
    __shared__ float gmax2[128];
    __shared__ int   s_cnt;

    const int a    = blockIdx.x;
    const int tid  = threadIdx.x;
    const int lane = tid & 63;
    const int wv   = tid >> 6;
    const int l15  = lane & 15;
    const int kb   = (lane >> 4) * 8;

    const float ax = anch[6*a],   ay = anch[6*a+1];
    const float w  = anch[6*a+3], l  = anch[6*a+4], hh = anch[6*a+5];
    const float hw = w * 0.5f, hl = l * 0.5f;
    const float x0 = ax - hw, x1 = ax + hw, y0 = ay - hl, y1 = ay + hl;

    // B-fragments (W2^T) straight from precomputed global, reused all chunks.
    // wave wv owns output cols c0=wv*16+l15 and c1=c0+64.
    bf16x8 b00, b01, b10, b11;
    {
        const int c0 = wv*16 + l15, c1 = c0 + 64;
        b00 = *(const bf16x8*)&w2tg[c0*64 + kb];
        b01 = *(const bf16x8*)&w2tg[c0*64 + 32 + kb];
        b10 = *(const bf16x8*)&w2tg[c1*64 + kb];
        b11 = *(const bf16x8*)&w2tg[c1*64 + 32 + kb];
    }

    if (tid == 0) s_cnt = 0;
    if (tid < 64) {
        w1s[0][tid] = W1[tid]; w1s[1][tid] = W1[64+tid]; w1s[2][tid] = W1[128+tid];
        b1s[tid] = b1[tid];
    }
    __syncthreads();

    // ---- phase A: gather inside points (ballot-compacted, unordered) ----
    int cx0 = (int)floorf(x0 * CINV); if (cx0 < 0) cx0 = 0;
    int cx1 = (int)floorf(x1 * CINV); if (cx1 > GRID-1) cx1 = GRID-1;
    int cy0 = (int)floorf(y0 * CINV); if (cy0 < 0) cy0 = 0;
    int cy1 = (int)floorf(y1 * CINV); if (cy1 > GRID-1) cy1 = GRID-1;

    for (int cy = cy0; cy <= cy1; cy++)
        for (int cx = cx0; cx <= cx1; cx++) {
            int c = cy * GRID + cx;
            int p0 = cstart[c], p1 = cstart[c+1];
            for (int base = p0; base < p1; base += 256) {
                int i = base + tid;
                bool ins = false;
                float4 P;
                if (i < p1) {
                    P = binned[i];
                    ins = (P.x >= x0) & (P.x <= x1) & (P.y >= y0) & (P.y <= y1)
                        & (P.z >= 0.f) & (P.z <= hh);
                }
                unsigned long long m = __ballot(ins);
                int wbase;
                if (lane == 0) wbase = atomicAdd(&s_cnt, __popcll(m));
                wbase = __shfl(wbase, 0);
                if (ins) {
                    int pos = wbase + __popcll(m & ((1ull << lane) - 1ull));
                    if (pos < MAXP)   { spx[pos] = P.x - ax; spy[pos] = P.y - ay; spz[pos] = P.z; }
                    if (pos < IDXCAP) sidx[pos] = __float_as_int(P.w);
                }
            }
        }
    __syncthreads();
    const int cnt = s_cnt;

    if (cnt < MINP) {               // zeroed row (valid==0), covers cnt==0
        if (tid < 5) out[5*a + tid] = 0.f;
        return;
    }

    // ---- rare fallback: cnt>512 needs "first 512 by original index" ----
    if (cnt > MAXP) {
        for (int i = cnt + tid; i < IDXCAP; i += 256) sidx[i] = 0x7fffffff;
        __syncthreads();
        for (int k = 2; k <= IDXCAP; k <<= 1) {
            for (int j = k >> 1; j > 0; j >>= 1) {
                #pragma unroll
                for (int e = 0; e < IDXCAP/256; e++) {
                    int i = tid + e*256;
                    int partner = i ^ j;
                    if (partner > i) {
                        int va = sidx[i], vb = sidx[partner];
                        bool up = ((i & k) == 0);
                        if ((va > vb) == up) { sidx[i] = vb; sidx[partner] = va; }
                    }
                }
                __syncthreads();
            }
        }
        for (int i = tid; i < MAXP; i += 256) {
            int idx = sidx[i];
            spx[i] = pts[3*idx]   - ax;
            spy[i] = pts[3*idx+1] - ay;
            spz[i] = pts[3*idx+2];
        }
        __syncthreads();
    }

    // ---- pad to multiple of 64 with copies of point 0 (max-invariant) ----
    const int gathered = cnt < MAXP ? cnt : MAXP;
    const int padded   = (gathered + 63) & ~63;
    for (int i = gathered + tid; i < padded; i += 256) {
        spx[i] = spx[0]; spy[i] = spy[0]; spz[i] = spz[0];
    }
    __syncthreads();

    // ---- phase B: layer1 (fp32->bf16) + MFMA layer2, 64-point chunks ----
    float gm0 = -INFINITY, gm1 = -INFINITY;   // raw max (bias+relu deferred)
    const int pairid = tid & 31;              // h1 dims 2*pairid, 2*pairid+1
    const int rowg   = tid >> 5;              // 0..7

    for (int pb = 0; pb < padded; pb += 64) {
        // layer 1: h1[64][64] bf16 into swizzled LDS
        #pragma unroll
        for (int pass = 0; pass < 8; pass++) {
            int row = pass*8 + rowg;
            int p = pb + row;
            float qx = spx[p], qy = spy[p], qz = spz[p];
            int d0 = pairid * 2;
            float v0 = fmaf(qz, w1s[2][d0],   fmaf(qy, w1s[1][d0],   fmaf(qx, w1s[0][d0],   b1s[d0])));
            float v1 = fmaf(qz, w1s[2][d0+1], fmaf(qy, w1s[1][d0+1], fmaf(qx, w1s[0][d0+1], b1s[d0+1])));
            v0 = fmaxf(v0, 0.f); v1 = fmaxf(v1, 0.f);
            uint32_t pk = (uint32_t)f2bf(v0) | ((uint32_t)f2bf(v1) << 16);
            int idx = (row*64 + d0) ^ ((row & 7) << 3);
            *(uint32_t*)&h1b[idx] = pk;
        }
        __syncthreads();

        #pragma unroll
        for (int mt = 0; mt < 4; mt++) {
            int r = mt*16 + l15;
            int ai0 = (r*64 +      kb) ^ ((r & 7) << 3);
            int ai1 = (r*64 + 32 + kb) ^ ((r & 7) << 3);
            bf16x8 a0 = *(const bf16x8*)&h1b[ai0];
            bf16x8 a1 = *(const bf16x8*)&h1b[ai1];
            f32x4 z = {0.f, 0.f, 0.f, 0.f};
            f32x4 c;
            c = __builtin_amdgcn_mfma_f32_16x16x32_bf16(a0, b00, z, 0, 0, 0);
            c = __builtin_amdgcn_mfma_f32_16x16x32_bf16(a1, b01, c, 0, 0, 0);
            gm0 = fmaxf(gm0, fmaxf(fmaxf(c[0], c[1]), fmaxf(c[2], c[3])));
            c = __builtin_amdgcn_mfma_f32_16x16x32_bf16(a0, b10, z, 0, 0, 0);
            c = __builtin_amdgcn_mfma_f32_16x16x32_bf16(a1, b11, c, 0, 0, 0);
            gm1 = fmaxf(gm1, fmaxf(fmaxf(c[0], c[1]), fmaxf(c[2], c[3])));
        }
        __syncthreads();   // before next chunk overwrites h1b
    }

    // reduce across the 4 row-groups (lanes L, L^16, L^32, L^48 share col)
    gm0 = fmaxf(gm0, __shfl_xor(gm0, 16)); gm0 = fmaxf(gm0, __shfl_xor(gm0, 32));
    gm1 = fmaxf(gm1, __shfl_xor(gm1, 16)); gm1 = fmaxf(gm1, __shfl_xor(gm1, 32));
    if (lane < 16) {
        gmax2[wv*16     + lane] = gm0;
        gmax2[(wv+4)*16 + lane] = gm1;
    }
    __syncthreads();
    if (tid < 128) gmax2[tid] = fmaxf(gmax2[tid] + b2[tid], 0.f);   // bias + relu
    __syncthreads();

    // final heads: out = [g@Wc+bc, g@Wr+br]
    if (tid < 5) {
        const float* Wv; float bias; int stride;
        if (tid == 0) { Wv = Wc;            bias = bc[0];      stride = 1; }
        else          { Wv = Wr + (tid-1);  bias = br[tid-1];  stride = 4; }
        float acc = bias;
        for (int i = 0; i < 128; i++) acc = fmaf(gmax2[i], Wv[i*stride], acc);
        out[5*a + tid] = acc;
    }
}

// ---------------- launch ----------------

extern "C" void kernel_launch(void* const* d_in, const int* in_sizes, int n_in,
                              void* d_out, int out_size, void* d_ws, size_t ws_size,
                              hipStream_t stream) {
    const float* pts  = (const float*)d_in[0];
    const float* anch = (const float*)d_in[1];
    const float* W1   = (const float*)d_in[2];
    const float* b1   = (const float*)d_in[3];
    const float* W2   = (const float*)d_in[4];
    const float* b2   = (const float*)d_in[5];
    const float* Wc   = (const float*)d_in[6];
    const float* bc   = (const float*)d_in[7];
    const float* Wr   = (const float*)d_in[8];
    const float* br   = (const float*)d_in[9];
    float* out = (float*)d_out;

    char* ws = (char*)d_ws;
    float4*         binned    = (float4*)ws;                    // NPTS float4 (2MB @0)
    int*            blockhist = (int*)(ws + (size_t)NPTS*16);   // HB*NCELL ints (320KB)
    int*            blockpre  = blockhist + HB*NCELL;           // HB*NCELL ints (320KB)
    int*            cstart    = blockpre  + HB*NCELL;           // NCELL+1 ints
    int*            cellrank  = cstart + 1024;                  // NPTS ints (512KB)
    unsigned short* w2tg      = (unsigned short*)(cellrank + NPTS);  // 128*64 bf16 (16KB)

    k_hist   <<<HB, 256, 0, stream>>>(pts, blockhist, cellrank);
    k_scan   <<<1, 1024, 0, stream>>>(blockhist, blockpre, cstart, W2, w2tg);
    k_scatter<<<HB, 256, 0, stream>>>(pts, cellrank, blockpre, cstart, binned);
    k_main   <<<NANCH, 256, 0, stream>>>(pts, anch, W1, b1, b2, Wc, bc, Wr, br,
                                         w2tg, binned, cstart, out);
}